// Round 18
// baseline (375.074 us; speedup 1.0000x reference)
//
#include <hip/hip_runtime.h>
#include <math.h>

#define NN 50000
#define NE 800000
#define D  256
#define SCB 196   // ceil(NN/256)
#define NB2 391   // ceil(NN/128) — row-blocks

typedef unsigned short u16;
typedef __attribute__((ext_vector_type(8))) short short8;
typedef __attribute__((ext_vector_type(8))) unsigned short u16x8;
typedef __attribute__((ext_vector_type(4))) float f32x4;

__device__ __forceinline__ u16 f2b(float f) {
    unsigned u = __float_as_uint(f);
    return (u16)((u + 0x7FFFu + ((u >> 16) & 1u)) >> 16);
}
__device__ __forceinline__ float b2f(u16 b) {
    return __uint_as_float(((unsigned)b) << 16);
}

__device__ __forceinline__ void gl16(const u16* g, u16* l) {
    __builtin_amdgcn_global_load_lds(
        (const __attribute__((address_space(1))) void*)g,
        (__attribute__((address_space(3))) void*)l, 16, 0, 0);
}

// ---------------- merged x-conv + weight pack + degree count ----------------
__global__ void wxconv_kernel(const float* __restrict__ x,
                              const float* __restrict__ W1l, const float* __restrict__ W1r,
                              const float* __restrict__ W2l, const float* __restrict__ W2r,
                              const int* __restrict__ dst,
                              u16* __restrict__ Acat,
                              u16* __restrict__ Wcat1, u16* __restrict__ Wcat2,
                              int* __restrict__ deg) {
    int b = blockIdx.x;
    if (b < 12500) {
        int idx = b * 256 + threadIdx.x;
        int r = idx >> 6;
        int c4 = (idx & 63) * 4;
        float4 v = *(const float4*)&x[(size_t)r * 256 + c4];
        ushort4 o;
        o.x = f2b(v.x); o.y = f2b(v.y); o.z = f2b(v.z); o.w = f2b(v.w);
        *(ushort4*)&Acat[(size_t)r * 512 + 256 + c4] = o;
    } else if (b < 12756) {
        int r = b - 12500;
        int j = threadIdx.x;
        Wcat1[r * 512 + j]       = f2b(W1l[r * 256 + j]);
        Wcat1[r * 512 + 256 + j] = f2b(W1r[r * 256 + j]);
        Wcat2[r * 512 + j]       = f2b(W2l[r * 256 + j]);
        Wcat2[r * 512 + 256 + j] = f2b(W2r[r * 256 + j]);
    } else {
        int e0 = ((b - 12756) * 256 + threadIdx.x) * 4;
        if (e0 + 3 < NE) {
            int4 d = *(const int4*)&dst[e0];
            atomicAdd(&deg[d.x], 1);
            atomicAdd(&deg[d.y], 1);
            atomicAdd(&deg[d.z], 1);
            atomicAdd(&deg[d.w], 1);
        } else {
            for (int e = e0; e < NE; e++) atomicAdd(&deg[dst[e]], 1);
        }
    }
}

// ---------------- CSR scan ----------------
__global__ void scanA_kernel(const int* __restrict__ deg, int* __restrict__ partial) {
    int t = threadIdx.x;
    int i = blockIdx.x * 256 + t;
    int v = (i < NN) ? deg[i] : 0;
#pragma unroll
    for (int o = 32; o; o >>= 1) v += __shfl_xor(v, o);
    __shared__ int sm[4];
    if ((t & 63) == 0) sm[t >> 6] = v;
    __syncthreads();
    if (t == 0) partial[blockIdx.x] = sm[0] + sm[1] + sm[2] + sm[3];
}

__global__ void scanC_kernel(const int* __restrict__ deg, const int* __restrict__ partial,
                             int* __restrict__ offs, int* __restrict__ cur) {
    __shared__ int smp[256];
    __shared__ int sm[256];
    int t = threadIdx.x;
    int pv = (t < SCB) ? partial[t] : 0;
    smp[t] = pv;
    __syncthreads();
    for (int off = 1; off < 256; off <<= 1) {
        int u = 0;
        if (t >= off) u = smp[t - off];
        __syncthreads();
        smp[t] += u;
        __syncthreads();
    }
    int bid = blockIdx.x;
    int blockbase = (bid > 0) ? smp[bid - 1] : 0;
    if (bid == SCB - 1 && t == 255) offs[NN] = smp[255];

    int i = bid * 256 + t;
    int v = (i < NN) ? deg[i] : 0;
    sm[t] = v;
    __syncthreads();
    for (int off = 1; off < 256; off <<= 1) {
        int u = 0;
        if (t >= off) u = sm[t - off];
        __syncthreads();
        sm[t] += u;
        __syncthreads();
    }
    int o = blockbase + sm[t] - v;
    if (i < NN) {
        offs[i] = o;
        cur[i] = o;
    }
}

__global__ void fill_kernel(const int* __restrict__ src, const int* __restrict__ dst,
                            int* __restrict__ cur, int* __restrict__ csr) {
    int e0 = (blockIdx.x * blockDim.x + threadIdx.x) * 8;
    if (e0 + 7 < NE) {
        int4 d0 = *(const int4*)&dst[e0];
        int4 d1 = *(const int4*)&dst[e0 + 4];
        int4 s0 = *(const int4*)&src[e0];
        int4 s1 = *(const int4*)&src[e0 + 4];
        int p0 = atomicAdd(&cur[d0.x], 1);
        int p1 = atomicAdd(&cur[d0.y], 1);
        int p2 = atomicAdd(&cur[d0.z], 1);
        int p3 = atomicAdd(&cur[d0.w], 1);
        int p4 = atomicAdd(&cur[d1.x], 1);
        int p5 = atomicAdd(&cur[d1.y], 1);
        int p6 = atomicAdd(&cur[d1.z], 1);
        int p7 = atomicAdd(&cur[d1.w], 1);
        csr[p0] = s0.x; csr[p1] = s0.y; csr[p2] = s0.z; csr[p3] = s0.w;
        csr[p4] = s1.x; csr[p5] = s1.y; csr[p6] = s1.z; csr[p7] = s1.w;
    } else {
        for (int e = e0; e < NE; e++) {
            int pos = atomicAdd(&cur[dst[e]], 1);
            csr[pos] = src[e];
        }
    }
}

// ---------------- mean aggregation: one wave per node, 8 gathers in flight --
__global__ __launch_bounds__(256)
void agg_kernel(const u16* __restrict__ Acat, const int* __restrict__ csr,
                const int* __restrict__ offs, u16* __restrict__ AcatW) {
    int wid = (blockIdx.x * blockDim.x + threadIdx.x) >> 6;
    int lane = threadIdx.x & 63;
    if (wid >= NN) return;
    int beg = offs[wid];
    int end = offs[wid + 1];
    int deg = end - beg;
    int half = lane >> 5;
    int lc = (lane & 31) * 8;
    int mid = beg + ((deg + 1) >> 1);
    int e  = half ? mid : beg;
    int hi = half ? end : mid;
    float a[8] = {0.f, 0.f, 0.f, 0.f, 0.f, 0.f, 0.f, 0.f};
    for (; e + 7 < hi; e += 8) {
        int s0 = csr[e + 0], s1 = csr[e + 1], s2 = csr[e + 2], s3 = csr[e + 3];
        int s4 = csr[e + 4], s5 = csr[e + 5], s6 = csr[e + 6], s7 = csr[e + 7];
        u16x8 v0 = *(const u16x8*)&Acat[(size_t)s0 * 512 + 256 + lc];
        u16x8 v1 = *(const u16x8*)&Acat[(size_t)s1 * 512 + 256 + lc];
        u16x8 v2 = *(const u16x8*)&Acat[(size_t)s2 * 512 + 256 + lc];
        u16x8 v3 = *(const u16x8*)&Acat[(size_t)s3 * 512 + 256 + lc];
        u16x8 v4 = *(const u16x8*)&Acat[(size_t)s4 * 512 + 256 + lc];
        u16x8 v5 = *(const u16x8*)&Acat[(size_t)s5 * 512 + 256 + lc];
        u16x8 v6 = *(const u16x8*)&Acat[(size_t)s6 * 512 + 256 + lc];
        u16x8 v7 = *(const u16x8*)&Acat[(size_t)s7 * 512 + 256 + lc];
#pragma unroll
        for (int i = 0; i < 8; i++)
            a[i] += ((b2f(v0[i]) + b2f(v1[i])) + (b2f(v2[i]) + b2f(v3[i]))) +
                    ((b2f(v4[i]) + b2f(v5[i])) + (b2f(v6[i]) + b2f(v7[i])));
    }
    for (; e + 3 < hi; e += 4) {
        int s0 = csr[e + 0], s1 = csr[e + 1], s2 = csr[e + 2], s3 = csr[e + 3];
        u16x8 v0 = *(const u16x8*)&Acat[(size_t)s0 * 512 + 256 + lc];
        u16x8 v1 = *(const u16x8*)&Acat[(size_t)s1 * 512 + 256 + lc];
        u16x8 v2 = *(const u16x8*)&Acat[(size_t)s2 * 512 + 256 + lc];
        u16x8 v3 = *(const u16x8*)&Acat[(size_t)s3 * 512 + 256 + lc];
#pragma unroll
        for (int i = 0; i < 8; i++)
            a[i] += (b2f(v0[i]) + b2f(v1[i])) + (b2f(v2[i]) + b2f(v3[i]));
    }
    for (; e < hi; e++) {
        int s0 = csr[e];
        u16x8 v0 = *(const u16x8*)&Acat[(size_t)s0 * 512 + 256 + lc];
#pragma unroll
        for (int i = 0; i < 8; i++) a[i] += b2f(v0[i]);
    }
#pragma unroll
    for (int i = 0; i < 8; i++) a[i] += __shfl_xor(a[i], 32);
    float sc = (deg > 0) ? 1.0f / (float)deg : 0.0f;
    if (half == 0) {
        u16x8 o;
#pragma unroll
        for (int i = 0; i < 8; i++) o[i] = f2b(a[i] * sc);
        *(u16x8*)&AcatW[(size_t)wid * 512 + lc] = o;
    }
}

// ---------------- GEMM-1: 128x128 tile, 8 waves, grid (391,2) ---------------
// 3-buffer ring (48 KB -> 3 blocks/CU, ~24 waves/CU offered), counted vmcnt(2).
// Fused BN-stats: per-block column sum/sumsq partials -> spart[782][256]
// (no atomics — R10 lesson: partials-then-reduce).
__global__ __launch_bounds__(512)
void gemm1_kernel(const u16* __restrict__ A, const u16* __restrict__ W,
                  const float* __restrict__ bias, u16* __restrict__ Cout,
                  float* __restrict__ spart) {
    __shared__ u16 As[3][128 * 32];   // 24 KB
    __shared__ u16 Bs[3][128 * 32];   // 24 KB
    const int tid = threadIdx.x;
    const int l = tid & 63;
    const int wid = tid >> 6;          // 0..7
    const int wr = wid >> 1;           // 0..3 (32 rows each)
    const int wc = wid & 1;            // 0..1 (64 cols each)
    const int row0 = blockIdx.x * 128;
    const int col0 = blockIdx.y * 128;

    const u16* aptr;
    const u16* bptr;
    {
        int row = wid * 16 + (l >> 2);
        int kg = (l & 3) ^ ((row >> 1) & 3);
        int ra = row0 + row;
        if (ra > NN - 1) ra = NN - 1;
        aptr = A + (size_t)ra * 512 + kg * 8;
        bptr = W + (size_t)(col0 + row) * 512 + kg * 8;
    }

    f32x4 acc[2][4] = {};

#define STG1(b, t)                                              \
    do {                                                        \
        gl16(aptr + (t) * 32, &As[b][(wid * 16) * 32]);         \
        gl16(bptr + (t) * 32, &Bs[b][(wid * 16) * 32]);         \
    } while (0)

    STG1(0, 0);
    STG1(1, 1);

    const int kq = l >> 4;
    const int sw = ((l & 15) >> 1) & 3;
#pragma unroll
    for (int t = 0; t < 16; t++) {
        if (t < 15) asm volatile("s_waitcnt vmcnt(2)" ::: "memory");
        else        asm volatile("s_waitcnt vmcnt(0)" ::: "memory");
        __builtin_amdgcn_s_barrier();
        __builtin_amdgcn_sched_barrier(0);

        if (t + 2 < 16) STG1((t + 2) % 3, t + 2);

        short8 af[2], bf[4];
#pragma unroll
        for (int m = 0; m < 2; m++) {
            int row = wr * 32 + m * 16 + (l & 15);
            af[m] = *(const short8*)&As[t % 3][row * 32 + (kq ^ sw) * 8];
        }
#pragma unroll
        for (int n = 0; n < 4; n++) {
            int row = wc * 64 + n * 16 + (l & 15);
            bf[n] = *(const short8*)&Bs[t % 3][row * 32 + (kq ^ sw) * 8];
        }
#pragma unroll
        for (int m = 0; m < 2; m++)
#pragma unroll
            for (int n = 0; n < 4; n++)
                acc[m][n] = __builtin_amdgcn_mfma_f32_16x16x32_bf16(
                    af[m], bf[n], acc[m][n], 0, 0, 0);
    }
#undef STG1

    // epilogue: store + column partials (sum, sumsq)
    const int cq = l >> 4;
    const int cc = l & 15;
    float t0[4] = {0.f, 0.f, 0.f, 0.f};
    float t1[4] = {0.f, 0.f, 0.f, 0.f};
#pragma unroll
    for (int m = 0; m < 2; m++) {
#pragma unroll
        for (int n = 0; n < 4; n++) {
            int c = col0 + wc * 64 + n * 16 + cc;
#pragma unroll
            for (int j = 0; j < 4; j++) {
                int r = row0 + wr * 32 + m * 16 + cq * 4 + j;
                if (r < NN) {
                    float v = acc[m][n][j] + bias[c];
                    Cout[(size_t)r * 256 + c] = f2b(v);
                    t0[n] += v;
                    t1[n] += v * v;
                }
            }
        }
    }
    // reduce over cq groups (this wave's 32 rows)
#pragma unroll
    for (int n = 0; n < 4; n++) {
        t0[n] += __shfl_xor(t0[n], 16); t1[n] += __shfl_xor(t1[n], 16);
        t0[n] += __shfl_xor(t0[n], 32); t1[n] += __shfl_xor(t1[n], 32);
    }
    // combine over wr via LDS (buffers no longer needed)
    __syncthreads();
    float* sred = (float*)&As[0][0];   // [4][256]: per-wr {sum[128], sumsq[128]}
    if (cq == 0) {
#pragma unroll
        for (int n = 0; n < 4; n++) {
            int cl = wc * 64 + n * 16 + cc;
            sred[wr * 256 + cl] = t0[n];
            sred[wr * 256 + 128 + cl] = t1[n];
        }
    }
    __syncthreads();
    if (tid < 256) {
        float s = sred[tid] + sred[256 + tid] + sred[512 + tid] + sred[768 + tid];
        spart[(size_t)(blockIdx.x * 2 + blockIdx.y) * 256 + tid] = s;
    }
}

// ---------------- stats finalize: reduce spart -> scale/shift ----------------
__global__ void statsfin_kernel(const float* __restrict__ spart,
                                const float* __restrict__ gamma,
                                const float* __restrict__ beta,
                                float* __restrict__ scale,
                                float* __restrict__ shift) {
    int c = threadIdx.x;          // 0..255
    int by = c >> 7, cl = c & 127;
    float su = 0.f, sq = 0.f;
#pragma unroll 4
    for (int bx = 0; bx < NB2; bx++) {
        const float* p = spart + (size_t)(bx * 2 + by) * 256 + cl;
        su += p[0];
        sq += p[128];
    }
    const float invN = 1.0f / (float)NN;
    float mu = su * invN;
    float var = sq * invN - mu * mu;
    float sc = gamma[c] * rsqrtf(var + 1e-5f);
    scale[c] = sc;
    shift[c] = beta[c] - mu * sc;
}

// ---------------- GEMM-2: 128x256 tile, 8 waves, fused L2-norm + colsum ----
__global__ __launch_bounds__(512)
void gemm2_l2_kernel(const u16* __restrict__ A, const u16* __restrict__ W,
                     const float* __restrict__ bias, float* __restrict__ out,
                     float* __restrict__ colsum_part) {
    __shared__ u16 As[3][128 * 32];
    __shared__ u16 Bs[3][256 * 32];
    const int tid = threadIdx.x;
    const int l = tid & 63;
    const int wid = tid >> 6;
    const int wr = wid >> 2;
    const int wc = wid & 3;
    const int row0 = blockIdx.x * 128;

    const u16* aptr;
    const u16* bptr[2];
    {
        int row = wid * 16 + (l >> 2);
        int kg = (l & 3) ^ ((row >> 1) & 3);
        int ra = row0 + row;
        if (ra > NN - 1) ra = NN - 1;
        aptr = A + (size_t)ra * 512 + kg * 8;
    }
#pragma unroll
    for (int i = 0; i < 2; i++) {
        int row = wid * 32 + i * 16 + (l >> 2);
        int kg = (l & 3) ^ ((row >> 1) & 3);
        bptr[i] = W + (size_t)row * 512 + kg * 8;
    }

    f32x4 acc[4][4] = {};

#define STAGE2(b, t)                                                         \
    do {                                                                     \
        gl16(aptr + (t) * 32, &As[b][(wid * 16) * 32]);                      \
        _Pragma("unroll") for (int i_ = 0; i_ < 2; i_++)                     \
            gl16(bptr[i_] + (t) * 32, &Bs[b][(wid * 32 + i_ * 16) * 32]);    \
    } while (0)

    STAGE2(0, 0);
    STAGE2(1, 1);

    const int kq = l >> 4;
    const int sw = ((l & 15) >> 1) & 3;
#pragma unroll
    for (int t = 0; t < 16; t++) {
        if (t < 15) asm volatile("s_waitcnt vmcnt(3)" ::: "memory");
        else        asm volatile("s_waitcnt vmcnt(0)" ::: "memory");
        __builtin_amdgcn_s_barrier();
        __builtin_amdgcn_sched_barrier(0);

        if (t + 2 < 16) STAGE2((t + 2) % 3, t + 2);

        short8 af[4], bf[4];
#pragma unroll
        for (int m = 0; m < 4; m++) {
            int row = wr * 64 + m * 16 + (l & 15);
            af[m] = *(const short8*)&As[t % 3][row * 32 + (kq ^ sw) * 8];
        }
#pragma unroll
        for (int n = 0; n < 4; n++) {
            int row = wc * 64 + n * 16 + (l & 15);
            bf[n] = *(const short8*)&Bs[t % 3][row * 32 + (kq ^ sw) * 8];
        }
#pragma unroll
        for (int m = 0; m < 4; m++)
#pragma unroll
            for (int n = 0; n < 4; n++)
                acc[m][n] = __builtin_amdgcn_mfma_f32_16x16x32_bf16(
                    af[m], bf[n], acc[m][n], 0, 0, 0);
    }
#undef STAGE2

    float* rowsq = (float*)&As[1][0];
    float* colp  = rowsq + 512;
    const int cq = l >> 4;
    const int cc = l & 15;

    float sq[4][4];
#pragma unroll
    for (int m = 0; m < 4; m++)
#pragma unroll
        for (int j = 0; j < 4; j++) {
            float s = 0.f;
#pragma unroll
            for (int n = 0; n < 4; n++) {
                float v = acc[m][n][j] + bias[wc * 64 + n * 16 + cc];
                acc[m][n][j] = v;
                s += v * v;
            }
            sq[m][j] = s;
        }
#pragma unroll
    for (int o = 1; o < 16; o <<= 1)
#pragma unroll
        for (int m = 0; m < 4; m++)
#pragma unroll
            for (int j = 0; j < 4; j++) sq[m][j] += __shfl_xor(sq[m][j], o);

    __syncthreads();
#pragma unroll
    for (int m = 0; m < 4; m++)
#pragma unroll
        for (int j = 0; j < 4; j++)
            if (cc == j) rowsq[wc * 128 + wr * 64 + m * 16 + cq * 4 + j] = sq[m][j];
    __syncthreads();

    float colpart[4] = {0.f, 0.f, 0.f, 0.f};
#pragma unroll
    for (int m = 0; m < 4; m++)
#pragma unroll
        for (int j = 0; j < 4; j++) {
            int rl = wr * 64 + m * 16 + cq * 4 + j;
            float s = rowsq[rl] + rowsq[128 + rl] + rowsq[256 + rl] + rowsq[384 + rl];
            float invn = 1.0f / fmaxf(sqrtf(s), 1e-12f);
            int r = row0 + rl;
            bool ok = (r < NN);
#pragma unroll
            for (int n = 0; n < 4; n++) {
                float vn = acc[m][n][j] * invn;
                if (ok) {
                    out[(size_t)r * 256 + wc * 64 + n * 16 + cc] = vn;
                    colpart[n] += vn;
                }
            }
        }
#pragma unroll
    for (int n = 0; n < 4; n++) {
        colpart[n] += __shfl_xor(colpart[n], 16);
        colpart[n] += __shfl_xor(colpart[n], 32);
    }
    if (l < 16) {
#pragma unroll
        for (int n = 0; n < 4; n++)
            colp[wr * 256 + wc * 64 + n * 16 + l] = colpart[n];
    }
    __syncthreads();
    if (tid < 256)
        colsum_part[(size_t)blockIdx.x * 256 + tid] = colp[tid] + colp[256 + tid];
}

// ---------------- BN + ReLU (reads precomputed scale/shift) ----------------
__global__ void bnrelu_kernel(const u16* __restrict__ hb,
                              const float* __restrict__ scale,
                              const float* __restrict__ shift,
                              u16* __restrict__ Acat) {
    __shared__ float s_scale[256], s_shift[256];
    int t = threadIdx.x;
    s_scale[t] = scale[t];
    s_shift[t] = shift[t];
    __syncthreads();
    int idx = blockIdx.x * 256 + t;
    int r = idx >> 5;
    int c8 = (idx & 31) * 8;
    u16x8 v = *(const u16x8*)&hb[(size_t)r * 256 + c8];
    u16x8 o;
#pragma unroll
    for (int i = 0; i < 8; i++) {
        float f = b2f(v[i]) * s_scale[c8 + i] + s_shift[c8 + i];
        o[i] = f2b(fmaxf(f, 0.f));
    }
    *(u16x8*)&Acat[(size_t)r * 512 + 256 + c8] = o;
}

// ---------------- graph embedding ----------------
__global__ void graph_kernel(const float* __restrict__ colsum_part,
                             float* __restrict__ gout) {
    __shared__ float wsum[4];
    int j = threadIdx.x;
    float s = 0.f;
#pragma unroll 8
    for (int b = 0; b < NB2; b++) s += colsum_part[(size_t)b * 256 + j];
    float v = s * (1.0f / (float)NN);
    float sq = v * v;
#pragma unroll
    for (int o = 32; o; o >>= 1) sq += __shfl_xor(sq, o);
    if ((j & 63) == 0) wsum[j >> 6] = sq;
    __syncthreads();
    float tot = wsum[0] + wsum[1] + wsum[2] + wsum[3];
    gout[j] = v / fmaxf(sqrtf(tot), 1e-12f);
}

extern "C" void kernel_launch(void* const* d_in, const int* in_sizes, int n_in,
                              void* d_out, int out_size, void* d_ws, size_t ws_size,
                              hipStream_t stream) {
    const float* x      = (const float*)d_in[0];
    const float* W1_l   = (const float*)d_in[1];
    const float* b1_l   = (const float*)d_in[2];
    const float* W1_r   = (const float*)d_in[3];
    const float* W2_l   = (const float*)d_in[4];
    const float* b2_l   = (const float*)d_in[5];
    const float* W2_r   = (const float*)d_in[6];
    const float* gamma1 = (const float*)d_in[7];
    const float* beta1  = (const float*)d_in[8];
    const int*   eidx   = (const int*)d_in[9];
    const int* src = eidx;
    const int* dst = eidx + NE;

    char* wsb = (char*)d_ws;
    int*   deg    = (int*)(wsb + 0);
    int*   offs   = (int*)(wsb + 200000);
    int*   cur    = (int*)(wsb + 400004);
    int*   csr    = (int*)(wsb + 600004);      // dead after agg-2; reused as cspart
    float* cspart = (float*)(wsb + 600004);    // [391][256] f32
    int*   part   = (int*)(wsb + 3800064);     // [256]
    float* scale  = (float*)(wsb + 3801088);   // [256]
    float* shift  = (float*)(wsb + 3802112);   // [256]
    u16*   Wcat1  = (u16*)(wsb + 3807232);
    u16*   Wcat2  = (u16*)(wsb + 4069376);
    u16*   hb     = (u16*)(wsb + 4331520);
    u16*   Acat   = (u16*)(wsb + 29931520);
    float* spart  = (float*)(wsb + 81131520);  // [782][256] f32 = 800 KB
    float* out    = (float*)d_out;
    float* gout   = out + (size_t)NN * 256;

    hipMemsetAsync(deg, 0, NN * sizeof(int), stream);

    const int DEGB = (NE / 4 + 255) / 256;
    wxconv_kernel<<<12756 + DEGB, 256, 0, stream>>>(x, W1_l, W1_r, W2_l, W2_r,
                                                    dst, Acat, Wcat1, Wcat2, deg);

    scanA_kernel<<<SCB, 256, 0, stream>>>(deg, part);
    scanC_kernel<<<SCB, 256, 0, stream>>>(deg, part, offs, cur);
    fill_kernel<<<(NE / 8 + 255) / 256, 256, 0, stream>>>(src, dst, cur, csr);

    // layer 1 (GEMM + fused column-stat partials)
    agg_kernel<<<12500, 256, 0, stream>>>(Acat, csr, offs, Acat);
    dim3 g1grid(NB2, 2);
    gemm1_kernel<<<g1grid, 512, 0, stream>>>(Acat, Wcat1, b1_l, hb, spart);
    statsfin_kernel<<<1, 256, 0, stream>>>(spart, gamma1, beta1, scale, shift);
    bnrelu_kernel<<<6250, 256, 0, stream>>>(hb, scale, shift, Acat);

    // layer 2 (GEMM + fused L2-normalize + colsum partials)
    agg_kernel<<<12500, 256, 0, stream>>>(Acat, csr, offs, Acat);
    gemm2_l2_kernel<<<NB2, 512, 0, stream>>>(Acat, Wcat2, b2_l, out, cspart);

    // graph embedding
    graph_kernel<<<1, 256, 0, stream>>>(cspart, gout);
}

// Round 19
// 328.432 us; speedup vs baseline: 1.1420x; 1.1420x over previous
//
#include <hip/hip_runtime.h>
#include <math.h>

#define NN 50000
#define NE 800000
#define D  256
#define SCB 196   // ceil(NN/256)
#define NB2 391   // ceil(NN/128) — row-blocks

typedef unsigned short u16;
typedef __attribute__((ext_vector_type(8))) short short8;
typedef __attribute__((ext_vector_type(8))) unsigned short u16x8;
typedef __attribute__((ext_vector_type(4))) float f32x4;

__device__ __forceinline__ u16 f2b(float f) {
    unsigned u = __float_as_uint(f);
    return (u16)((u + 0x7FFFu + ((u >> 16) & 1u)) >> 16);
}
__device__ __forceinline__ float b2f(u16 b) {
    return __uint_as_float(((unsigned)b) << 16);
}

__device__ __forceinline__ void gl16(const u16* g, u16* l) {
    __builtin_amdgcn_global_load_lds(
        (const __attribute__((address_space(1))) void*)g,
        (__attribute__((address_space(3))) void*)l, 16, 0, 0);
}

// ---------------- merged x-conv + weight pack + degree count ----------------
__global__ void wxconv_kernel(const float* __restrict__ x,
                              const float* __restrict__ W1l, const float* __restrict__ W1r,
                              const float* __restrict__ W2l, const float* __restrict__ W2r,
                              const int* __restrict__ dst,
                              u16* __restrict__ Acat,
                              u16* __restrict__ Wcat1, u16* __restrict__ Wcat2,
                              int* __restrict__ deg) {
    int b = blockIdx.x;
    if (b < 12500) {
        int idx = b * 256 + threadIdx.x;
        int r = idx >> 6;
        int c4 = (idx & 63) * 4;
        float4 v = *(const float4*)&x[(size_t)r * 256 + c4];
        ushort4 o;
        o.x = f2b(v.x); o.y = f2b(v.y); o.z = f2b(v.z); o.w = f2b(v.w);
        *(ushort4*)&Acat[(size_t)r * 512 + 256 + c4] = o;
    } else if (b < 12756) {
        int r = b - 12500;
        int j = threadIdx.x;
        Wcat1[r * 512 + j]       = f2b(W1l[r * 256 + j]);
        Wcat1[r * 512 + 256 + j] = f2b(W1r[r * 256 + j]);
        Wcat2[r * 512 + j]       = f2b(W2l[r * 256 + j]);
        Wcat2[r * 512 + 256 + j] = f2b(W2r[r * 256 + j]);
    } else {
        int e0 = ((b - 12756) * 256 + threadIdx.x) * 4;
        if (e0 + 3 < NE) {
            int4 d = *(const int4*)&dst[e0];
            atomicAdd(&deg[d.x], 1);
            atomicAdd(&deg[d.y], 1);
            atomicAdd(&deg[d.z], 1);
            atomicAdd(&deg[d.w], 1);
        } else {
            for (int e = e0; e < NE; e++) atomicAdd(&deg[dst[e]], 1);
        }
    }
}

// ---------------- CSR scan (scanB folded into scanC) ----------------
__global__ void scanA_kernel(const int* __restrict__ deg, int* __restrict__ partial) {
    int t = threadIdx.x;
    int i = blockIdx.x * 256 + t;
    int v = (i < NN) ? deg[i] : 0;
#pragma unroll
    for (int o = 32; o; o >>= 1) v += __shfl_xor(v, o);
    __shared__ int sm[4];
    if ((t & 63) == 0) sm[t >> 6] = v;
    __syncthreads();
    if (t == 0) partial[blockIdx.x] = sm[0] + sm[1] + sm[2] + sm[3];
}

__global__ void scanC_kernel(const int* __restrict__ deg, const int* __restrict__ partial,
                             int* __restrict__ offs, int* __restrict__ cur) {
    __shared__ int smp[256];
    __shared__ int sm[256];
    int t = threadIdx.x;
    int pv = (t < SCB) ? partial[t] : 0;
    smp[t] = pv;
    __syncthreads();
    for (int off = 1; off < 256; off <<= 1) {
        int u = 0;
        if (t >= off) u = smp[t - off];
        __syncthreads();
        smp[t] += u;
        __syncthreads();
    }
    int bid = blockIdx.x;
    int blockbase = (bid > 0) ? smp[bid - 1] : 0;
    if (bid == SCB - 1 && t == 255) offs[NN] = smp[255];

    int i = bid * 256 + t;
    int v = (i < NN) ? deg[i] : 0;
    sm[t] = v;
    __syncthreads();
    for (int off = 1; off < 256; off <<= 1) {
        int u = 0;
        if (t >= off) u = sm[t - off];
        __syncthreads();
        sm[t] += u;
        __syncthreads();
    }
    int o = blockbase + sm[t] - v;
    if (i < NN) {
        offs[i] = o;
        cur[i] = o;
    }
}

__global__ void fill_kernel(const int* __restrict__ src, const int* __restrict__ dst,
                            int* __restrict__ cur, int* __restrict__ csr) {
    int e0 = (blockIdx.x * blockDim.x + threadIdx.x) * 8;
    if (e0 + 7 < NE) {
        int4 d0 = *(const int4*)&dst[e0];
        int4 d1 = *(const int4*)&dst[e0 + 4];
        int4 s0 = *(const int4*)&src[e0];
        int4 s1 = *(const int4*)&src[e0 + 4];
        int p0 = atomicAdd(&cur[d0.x], 1);
        int p1 = atomicAdd(&cur[d0.y], 1);
        int p2 = atomicAdd(&cur[d0.z], 1);
        int p3 = atomicAdd(&cur[d0.w], 1);
        int p4 = atomicAdd(&cur[d1.x], 1);
        int p5 = atomicAdd(&cur[d1.y], 1);
        int p6 = atomicAdd(&cur[d1.z], 1);
        int p7 = atomicAdd(&cur[d1.w], 1);
        csr[p0] = s0.x; csr[p1] = s0.y; csr[p2] = s0.z; csr[p3] = s0.w;
        csr[p4] = s1.x; csr[p5] = s1.y; csr[p6] = s1.z; csr[p7] = s1.w;
    } else {
        for (int e = e0; e < NE; e++) {
            int pos = atomicAdd(&cur[dst[e]], 1);
            csr[pos] = src[e];
        }
    }
}

// ---------------- mean aggregation: one wave per node, 8 gathers in flight --
__global__ __launch_bounds__(256)
void agg_kernel(const u16* __restrict__ Acat, const int* __restrict__ csr,
                const int* __restrict__ offs, u16* __restrict__ AcatW) {
    int wid = (blockIdx.x * blockDim.x + threadIdx.x) >> 6;
    int lane = threadIdx.x & 63;
    if (wid >= NN) return;
    int beg = offs[wid];
    int end = offs[wid + 1];
    int deg = end - beg;
    int half = lane >> 5;
    int lc = (lane & 31) * 8;
    int mid = beg + ((deg + 1) >> 1);
    int e  = half ? mid : beg;
    int hi = half ? end : mid;
    float a[8] = {0.f, 0.f, 0.f, 0.f, 0.f, 0.f, 0.f, 0.f};
    for (; e + 7 < hi; e += 8) {
        int s0 = csr[e + 0], s1 = csr[e + 1], s2 = csr[e + 2], s3 = csr[e + 3];
        int s4 = csr[e + 4], s5 = csr[e + 5], s6 = csr[e + 6], s7 = csr[e + 7];
        u16x8 v0 = *(const u16x8*)&Acat[(size_t)s0 * 512 + 256 + lc];
        u16x8 v1 = *(const u16x8*)&Acat[(size_t)s1 * 512 + 256 + lc];
        u16x8 v2 = *(const u16x8*)&Acat[(size_t)s2 * 512 + 256 + lc];
        u16x8 v3 = *(const u16x8*)&Acat[(size_t)s3 * 512 + 256 + lc];
        u16x8 v4 = *(const u16x8*)&Acat[(size_t)s4 * 512 + 256 + lc];
        u16x8 v5 = *(const u16x8*)&Acat[(size_t)s5 * 512 + 256 + lc];
        u16x8 v6 = *(const u16x8*)&Acat[(size_t)s6 * 512 + 256 + lc];
        u16x8 v7 = *(const u16x8*)&Acat[(size_t)s7 * 512 + 256 + lc];
#pragma unroll
        for (int i = 0; i < 8; i++)
            a[i] += ((b2f(v0[i]) + b2f(v1[i])) + (b2f(v2[i]) + b2f(v3[i]))) +
                    ((b2f(v4[i]) + b2f(v5[i])) + (b2f(v6[i]) + b2f(v7[i])));
    }
    for (; e + 3 < hi; e += 4) {
        int s0 = csr[e + 0], s1 = csr[e + 1], s2 = csr[e + 2], s3 = csr[e + 3];
        u16x8 v0 = *(const u16x8*)&Acat[(size_t)s0 * 512 + 256 + lc];
        u16x8 v1 = *(const u16x8*)&Acat[(size_t)s1 * 512 + 256 + lc];
        u16x8 v2 = *(const u16x8*)&Acat[(size_t)s2 * 512 + 256 + lc];
        u16x8 v3 = *(const u16x8*)&Acat[(size_t)s3 * 512 + 256 + lc];
#pragma unroll
        for (int i = 0; i < 8; i++)
            a[i] += (b2f(v0[i]) + b2f(v1[i])) + (b2f(v2[i]) + b2f(v3[i]));
    }
    for (; e < hi; e++) {
        int s0 = csr[e];
        u16x8 v0 = *(const u16x8*)&Acat[(size_t)s0 * 512 + 256 + lc];
#pragma unroll
        for (int i = 0; i < 8; i++) a[i] += b2f(v0[i]);
    }
#pragma unroll
    for (int i = 0; i < 8; i++) a[i] += __shfl_xor(a[i], 32);
    float sc = (deg > 0) ? 1.0f / (float)deg : 0.0f;
    if (half == 0) {
        u16x8 o;
#pragma unroll
        for (int i = 0; i < 8; i++) o[i] = f2b(a[i] * sc);
        *(u16x8*)&AcatW[(size_t)wid * 512 + lc] = o;
    }
}

// ---------------- GEMM-1: 128x256 tile, 8 waves (bf16 out) ------------------
__global__ __launch_bounds__(512)
void mfma_gemm_kernel(const u16* __restrict__ A, const u16* __restrict__ W,
                      const float* __restrict__ bias, u16* __restrict__ Cout) {
    __shared__ u16 As[3][128 * 32];   // 24 KB
    __shared__ u16 Bs[3][256 * 32];   // 48 KB
    const int tid = threadIdx.x;
    const int l = tid & 63;
    const int wid = tid >> 6;          // 0..7
    const int wr = wid >> 2;           // 0..1
    const int wc = wid & 3;            // 0..3
    const int row0 = blockIdx.x * 128;

    const u16* aptr;
    const u16* bptr[2];
    {
        int row = wid * 16 + (l >> 2);
        int kg = (l & 3) ^ ((row >> 1) & 3);
        int ra = row0 + row;
        if (ra > NN - 1) ra = NN - 1;
        aptr = A + (size_t)ra * 512 + kg * 8;
    }
#pragma unroll
    for (int i = 0; i < 2; i++) {
        int row = wid * 32 + i * 16 + (l >> 2);
        int kg = (l & 3) ^ ((row >> 1) & 3);
        bptr[i] = W + (size_t)row * 512 + kg * 8;
    }

    f32x4 acc[4][4] = {};

#define STAGE1(b, t)                                                         \
    do {                                                                     \
        gl16(aptr + (t) * 32, &As[b][(wid * 16) * 32]);                      \
        _Pragma("unroll") for (int i_ = 0; i_ < 2; i_++)                     \
            gl16(bptr[i_] + (t) * 32, &Bs[b][(wid * 32 + i_ * 16) * 32]);    \
    } while (0)

    STAGE1(0, 0);
    STAGE1(1, 1);

    const int kq = l >> 4;
    const int sw = ((l & 15) >> 1) & 3;
#pragma unroll
    for (int t = 0; t < 16; t++) {
        if (t < 15) asm volatile("s_waitcnt vmcnt(3)" ::: "memory");
        else        asm volatile("s_waitcnt vmcnt(0)" ::: "memory");
        __builtin_amdgcn_s_barrier();
        __builtin_amdgcn_sched_barrier(0);

        if (t + 2 < 16) STAGE1((t + 2) % 3, t + 2);

        short8 af[4], bf[4];
#pragma unroll
        for (int m = 0; m < 4; m++) {
            int row = wr * 64 + m * 16 + (l & 15);
            af[m] = *(const short8*)&As[t % 3][row * 32 + (kq ^ sw) * 8];
        }
#pragma unroll
        for (int n = 0; n < 4; n++) {
            int row = wc * 64 + n * 16 + (l & 15);
            bf[n] = *(const short8*)&Bs[t % 3][row * 32 + (kq ^ sw) * 8];
        }
#pragma unroll
        for (int m = 0; m < 4; m++)
#pragma unroll
            for (int n = 0; n < 4; n++)
                acc[m][n] = __builtin_amdgcn_mfma_f32_16x16x32_bf16(
                    af[m], bf[n], acc[m][n], 0, 0, 0);
    }
#undef STAGE1

    const int cq = l >> 4;
    const int cc = l & 15;
#pragma unroll
    for (int m = 0; m < 4; m++) {
#pragma unroll
        for (int n = 0; n < 4; n++) {
            int c = wc * 64 + n * 16 + cc;
#pragma unroll
            for (int j = 0; j < 4; j++) {
                int r = row0 + wr * 64 + m * 16 + cq * 4 + j;
                if (r < NN)
                    Cout[(size_t)r * 256 + c] = f2b(acc[m][n][j] + bias[c]);
            }
        }
    }
}

// ---------------- GEMM-2: 128x256 tile, 8 waves, fused L2-norm + colsum ----
__global__ __launch_bounds__(512)
void gemm2_l2_kernel(const u16* __restrict__ A, const u16* __restrict__ W,
                     const float* __restrict__ bias, float* __restrict__ out,
                     float* __restrict__ colsum_part) {
    __shared__ u16 As[3][128 * 32];
    __shared__ u16 Bs[3][256 * 32];
    const int tid = threadIdx.x;
    const int l = tid & 63;
    const int wid = tid >> 6;
    const int wr = wid >> 2;
    const int wc = wid & 3;
    const int row0 = blockIdx.x * 128;

    const u16* aptr;
    const u16* bptr[2];
    {
        int row = wid * 16 + (l >> 2);
        int kg = (l & 3) ^ ((row >> 1) & 3);
        int ra = row0 + row;
        if (ra > NN - 1) ra = NN - 1;
        aptr = A + (size_t)ra * 512 + kg * 8;
    }
#pragma unroll
    for (int i = 0; i < 2; i++) {
        int row = wid * 32 + i * 16 + (l >> 2);
        int kg = (l & 3) ^ ((row >> 1) & 3);
        bptr[i] = W + (size_t)row * 512 + kg * 8;
    }

    f32x4 acc[4][4] = {};

#define STAGE2(b, t)                                                         \
    do {                                                                     \
        gl16(aptr + (t) * 32, &As[b][(wid * 16) * 32]);                      \
        _Pragma("unroll") for (int i_ = 0; i_ < 2; i_++)                     \
            gl16(bptr[i_] + (t) * 32, &Bs[b][(wid * 32 + i_ * 16) * 32]);    \
    } while (0)

    STAGE2(0, 0);
    STAGE2(1, 1);

    const int kq = l >> 4;
    const int sw = ((l & 15) >> 1) & 3;
#pragma unroll
    for (int t = 0; t < 16; t++) {
        if (t < 15) asm volatile("s_waitcnt vmcnt(3)" ::: "memory");
        else        asm volatile("s_waitcnt vmcnt(0)" ::: "memory");
        __builtin_amdgcn_s_barrier();
        __builtin_amdgcn_sched_barrier(0);

        if (t + 2 < 16) STAGE2((t + 2) % 3, t + 2);

        short8 af[4], bf[4];
#pragma unroll
        for (int m = 0; m < 4; m++) {
            int row = wr * 64 + m * 16 + (l & 15);
            af[m] = *(const short8*)&As[t % 3][row * 32 + (kq ^ sw) * 8];
        }
#pragma unroll
        for (int n = 0; n < 4; n++) {
            int row = wc * 64 + n * 16 + (l & 15);
            bf[n] = *(const short8*)&Bs[t % 3][row * 32 + (kq ^ sw) * 8];
        }
#pragma unroll
        for (int m = 0; m < 4; m++)
#pragma unroll
            for (int n = 0; n < 4; n++)
                acc[m][n] = __builtin_amdgcn_mfma_f32_16x16x32_bf16(
                    af[m], bf[n], acc[m][n], 0, 0, 0);
    }
#undef STAGE2

    // ---- epilogue ----
    float* rowsq = (float*)&As[1][0];   // [4][128]
    float* colp  = rowsq + 512;         // [2][256]
    const int cq = l >> 4;
    const int cc = l & 15;

    float sq[4][4];
#pragma unroll
    for (int m = 0; m < 4; m++)
#pragma unroll
        for (int j = 0; j < 4; j++) {
            float s = 0.f;
#pragma unroll
            for (int n = 0; n < 4; n++) {
                float v = acc[m][n][j] + bias[wc * 64 + n * 16 + cc];
                acc[m][n][j] = v;
                s += v * v;
            }
            sq[m][j] = s;
        }
#pragma unroll
    for (int o = 1; o < 16; o <<= 1)
#pragma unroll
        for (int m = 0; m < 4; m++)
#pragma unroll
            for (int j = 0; j < 4; j++) sq[m][j] += __shfl_xor(sq[m][j], o);

    __syncthreads();
#pragma unroll
    for (int m = 0; m < 4; m++)
#pragma unroll
        for (int j = 0; j < 4; j++)
            if (cc == j) rowsq[wc * 128 + wr * 64 + m * 16 + cq * 4 + j] = sq[m][j];
    __syncthreads();

    float colpart[4] = {0.f, 0.f, 0.f, 0.f};
#pragma unroll
    for (int m = 0; m < 4; m++)
#pragma unroll
        for (int j = 0; j < 4; j++) {
            int rl = wr * 64 + m * 16 + cq * 4 + j;
            float s = rowsq[rl] + rowsq[128 + rl] + rowsq[256 + rl] + rowsq[384 + rl];
            float invn = 1.0f / fmaxf(sqrtf(s), 1e-12f);
            int r = row0 + rl;
            bool ok = (r < NN);
#pragma unroll
            for (int n = 0; n < 4; n++) {
                float vn = acc[m][n][j] * invn;
                if (ok) {
                    out[(size_t)r * 256 + wc * 64 + n * 16 + cc] = vn;
                    colpart[n] += vn;
                }
            }
        }
#pragma unroll
    for (int n = 0; n < 4; n++) {
        colpart[n] += __shfl_xor(colpart[n], 16);
        colpart[n] += __shfl_xor(colpart[n], 32);
    }
    if (l < 16) {
#pragma unroll
        for (int n = 0; n < 4; n++)
            colp[wr * 256 + wc * 64 + n * 16 + l] = colpart[n];
    }
    __syncthreads();
    if (tid < 256)
        colsum_part[(size_t)blockIdx.x * 256 + tid] = colp[tid] + colp[256 + tid];
}

// ---------------- column stats: vectorized reads + 8-slot spread atomics ---
__global__ __launch_bounds__(256)
void colstats_kernel(const u16* __restrict__ h, float* __restrict__ stats8) {
    __shared__ float red[8][512];
    int t = threadIdx.x;
    int cg = (t & 31) * 8;
    int rofs = t >> 5;
    float s0[8] = {}, s1[8] = {};
    for (int r = blockIdx.x * 8 + rofs; r < NN; r += gridDim.x * 8) {
        u16x8 v = *(const u16x8*)&h[(size_t)r * 256 + cg];
#pragma unroll
        for (int i = 0; i < 8; i++) {
            float f = b2f(v[i]);
            s0[i] += f;
            s1[i] += f * f;
        }
    }
#pragma unroll
    for (int i = 0; i < 8; i++) {
        red[rofs][cg + i] = s0[i];
        red[rofs][256 + cg + i] = s1[i];
    }
    __syncthreads();
    float* slot = stats8 + (blockIdx.x & 7) * 512;
    for (int k = t; k < 512; k += 256) {
        float s = red[0][k] + red[1][k] + red[2][k] + red[3][k] +
                  red[4][k] + red[5][k] + red[6][k] + red[7][k];
        atomicAdd(&slot[k], s);
    }
}

// ---------------- BN + ReLU (reads 8-slot stats) ----------------
__global__ void bnrelu_kernel(const u16* __restrict__ hb,
                              const float* __restrict__ stats8,
                              const float* __restrict__ gamma,
                              const float* __restrict__ beta,
                              u16* __restrict__ Acat) {
    __shared__ float s_scale[256], s_shift[256];
    int t = threadIdx.x;
    {
        float su = 0.f, sq = 0.f;
#pragma unroll
        for (int k = 0; k < 8; k++) {
            su += stats8[k * 512 + t];
            sq += stats8[k * 512 + 256 + t];
        }
        const float invN = 1.0f / (float)NN;
        float mu = su * invN;
        float var = sq * invN - mu * mu;
        float sc = gamma[t] * rsqrtf(var + 1e-5f);
        s_scale[t] = sc;
        s_shift[t] = beta[t] - mu * sc;
    }
    __syncthreads();
    int idx = blockIdx.x * 256 + t;
    int r = idx >> 5;
    int c8 = (idx & 31) * 8;
    u16x8 v = *(const u16x8*)&hb[(size_t)r * 256 + c8];
    u16x8 o;
#pragma unroll
    for (int i = 0; i < 8; i++) {
        float f = b2f(v[i]) * s_scale[c8 + i] + s_shift[c8 + i];
        o[i] = f2b(fmaxf(f, 0.f));
    }
    *(u16x8*)&Acat[(size_t)r * 512 + 256 + c8] = o;
}

// ---------------- graph embedding ----------------
__global__ void graph_kernel(const float* __restrict__ colsum_part,
                             float* __restrict__ gout) {
    __shared__ float wsum[4];
    int j = threadIdx.x;
    float s = 0.f;
#pragma unroll 8
    for (int b = 0; b < NB2; b++) s += colsum_part[(size_t)b * 256 + j];
    float v = s * (1.0f / (float)NN);
    float sq = v * v;
#pragma unroll
    for (int o = 32; o; o >>= 1) sq += __shfl_xor(sq, o);
    if ((j & 63) == 0) wsum[j >> 6] = sq;
    __syncthreads();
    float tot = wsum[0] + wsum[1] + wsum[2] + wsum[3];
    gout[j] = v / fmaxf(sqrtf(tot), 1e-12f);
}

extern "C" void kernel_launch(void* const* d_in, const int* in_sizes, int n_in,
                              void* d_out, int out_size, void* d_ws, size_t ws_size,
                              hipStream_t stream) {
    const float* x      = (const float*)d_in[0];
    const float* W1_l   = (const float*)d_in[1];
    const float* b1_l   = (const float*)d_in[2];
    const float* W1_r   = (const float*)d_in[3];
    const float* W2_l   = (const float*)d_in[4];
    const float* b2_l   = (const float*)d_in[5];
    const float* W2_r   = (const float*)d_in[6];
    const float* gamma1 = (const float*)d_in[7];
    const float* beta1  = (const float*)d_in[8];
    const int*   eidx   = (const int*)d_in[9];
    const int* src = eidx;
    const int* dst = eidx + NE;

    char* wsb = (char*)d_ws;
    int*   deg    = (int*)(wsb + 0);
    int*   offs   = (int*)(wsb + 200000);
    int*   cur    = (int*)(wsb + 400004);      // dead after fill; reused as stats8
    float* stats8 = (float*)(wsb + 400004);    // [8][512] f32 = 16 KB
    int*   csr    = (int*)(wsb + 600004);      // dead after agg-2; reused as cspart
    float* cspart = (float*)(wsb + 600004);    // [391][256] f32
    int*   part   = (int*)(wsb + 3800064);
    u16*   Wcat1  = (u16*)(wsb + 3807232);
    u16*   Wcat2  = (u16*)(wsb + 4069376);
    u16*   hb     = (u16*)(wsb + 4331520);
    u16*   Acat   = (u16*)(wsb + 29931520);
    float* out    = (float*)d_out;
    float* gout   = out + (size_t)NN * 256;

    hipMemsetAsync(deg, 0, NN * sizeof(int), stream);

    const int DEGB = (NE / 4 + 255) / 256;
    wxconv_kernel<<<12756 + DEGB, 256, 0, stream>>>(x, W1_l, W1_r, W2_l, W2_r,
                                                    dst, Acat, Wcat1, Wcat2, deg);

    scanA_kernel<<<SCB, 256, 0, stream>>>(deg, part);
    scanC_kernel<<<SCB, 256, 0, stream>>>(deg, part, offs, cur);
    fill_kernel<<<(NE / 8 + 255) / 256, 256, 0, stream>>>(src, dst, cur, csr);
    // cur is dead now; zero stats8 in its place
    hipMemsetAsync(stats8, 0, 16384, stream);

    // layer 1
    agg_kernel<<<12500, 256, 0, stream>>>(Acat, csr, offs, Acat);
    mfma_gemm_kernel<<<NB2, 512, 0, stream>>>(Acat, Wcat1, b1_l, hb);
    colstats_kernel<<<256, 256, 0, stream>>>(hb, stats8);
    bnrelu_kernel<<<6250, 256, 0, stream>>>(hb, stats8, gamma1, beta1, Acat);

    // layer 2 (GEMM + fused L2-normalize + colsum partials)
    agg_kernel<<<12500, 256, 0, stream>>>(Acat, csr, offs, Acat);
    gemm2_l2_kernel<<<NB2, 512, 0, stream>>>(Acat, Wcat2, b2_l, out, cspart);

    // graph embedding
    graph_kernel<<<1, 256, 0, stream>>>(cspart, gout);
}